// Round 2
// baseline (249.212 us; speedup 1.0000x reference)
//
#include <hip/hip_runtime.h>

// GraphConv: out = relu( D * A_hat * D * x * W ),  B=8, N=2048, F=O=128, fp32.
// Reassociated: out[n,o] = relu( d[n] * sum_m A_hat[n,m] * y[m,o] ),
//   y[m,o] = d[m] * (x @ W)[m,o]  (stored transposed, bf16)
// K0: Wt = W^T bf16
// K1: d[b,n] = 1/(eps+sqrt(rowsum(A_hat)))       (one pass over adj)
// K2: y_t[b][o][m] = bf16(d*xW)                  (MFMA GEMM, K=128)
// K3: out = relu(d[n] * A_hat_bf16 @ y)          (MFMA GEMM, K=2048)
//
// R2: 32-row M-tile -> 512 blocks (2/CU), double-buffered LDS, ONE barrier
// per K-iter, next-iter global_load_lds + A-reg loads issued AFTER the
// barrier so they overlap the MFMA phase and only drain at the next barrier.

typedef __bf16 bf16x8 __attribute__((ext_vector_type(8)));
typedef __bf16 bf16x4 __attribute__((ext_vector_type(4)));
typedef float  f32x4  __attribute__((ext_vector_type(4)));

#define NN 2048
#define NB 8

__device__ __forceinline__ void load_lds16(__bf16* lds, const __bf16* g) {
    // per-lane global src; LDS dest = wave-uniform base + lane*16
    __builtin_amdgcn_global_load_lds(
        (const __attribute__((address_space(1))) void*)g,
        (__attribute__((address_space(3))) void*)lds, 16, 0, 0);
}

// ---------------- K0: W [128][128] fp32 -> Wt [o][f] bf16 ----------------
__global__ __launch_bounds__(256) void wt_kernel(const float* __restrict__ W,
                                                 __bf16* __restrict__ Wt) {
    int idx = blockIdx.x * 256 + threadIdx.x;   // grid 64 -> 16384
    int f = idx >> 7, o = idx & 127;
    Wt[o * 128 + f] = (__bf16)W[idx];
}

// ---------------- K1: degree vector ----------------
__global__ __launch_bounds__(256) void d_kernel(const float* __restrict__ adj,
                                                float* __restrict__ dvec) {
    const int lane = threadIdx.x & 63;
    const int row  = blockIdx.x * 4 + (threadIdx.x >> 6);   // one wave per row
    const float* rp = adj + (size_t)row * NN;
    float4 s4 = {0.f, 0.f, 0.f, 0.f};
#pragma unroll
    for (int it = 0; it < 8; ++it) {
        float4 v = *(const float4*)(rp + it * 256 + lane * 4);
        s4.x += v.x; s4.y += v.y; s4.z += v.z; s4.w += v.w;
    }
    float s = (s4.x + s4.y) + (s4.z + s4.w);
#pragma unroll
    for (int off = 32; off; off >>= 1) s += __shfl_down(s, off);
    if (lane == 0) {
        int n = row & (NN - 1);
        float sh = s - rp[n] + 1.0f;            // zero diag, add self-loop
        dvec[row] = 1.0f / (1e-6f + sqrtf(sh));
    }
}

// ---------------- K2/K3: MFMA GEMM, 32x128 tile, dbuf, 1 barrier/iter ----
// Block: 256 thr (4 waves). Wave w: rows (w&1)*16.., cols (w>>1)*64..
// A: [B*2048][KTOT] fp32, reg-prefetch -> cvt bf16 (+diag fix) -> LDS.
// Bmat: bf16, row = output col o, K-contiguous; staged via global_load_lds.
template <int KTOT, bool IS_XW>
__global__ __launch_bounds__(256) void gemm_kernel(
    const float* __restrict__ A, const __bf16* __restrict__ Bmat,
    const float* __restrict__ dvec, float* __restrict__ out,
    __bf16* __restrict__ yt) {
    __shared__ alignas(16) __bf16 sA[2][32][40];   // +8 pad rows
    __shared__ alignas(16) __bf16 sB[2][128][32];  // unpadded (glds layout)

    const int tid  = threadIdx.x;
    const int wave = tid >> 6;
    const int lane = tid & 63;
    // XCD swizzle: batch = blockIdx.x & 7 so each XCD's L2 keeps one y-slice
    const int b    = blockIdx.x & 7;
    const int tile = blockIdx.x >> 3;             // 0..63
    const int n_local_base = tile * 32;
    const int row_base = b * NN + n_local_base;

    const __bf16* Bptr = IS_XW ? Bmat : (Bmat + (size_t)b * 128 * KTOT);

    // A staging map: thread -> (row 0..31, 4 contiguous cols)
    const int a_row = tid >> 3;
    const int a_col = (tid & 7) * 4;
    const float* a_src = A + (size_t)(row_base + a_row) * KTOT + a_col;

    // B staging map: wave stages sB rows [wave*32, wave*32+32)
    const int b_row0 = wave * 32;
    const __bf16* b_src =
        Bptr + (size_t)(b_row0 + (lane >> 2)) * KTOT + (lane & 3) * 8;

    const int rsel = (wave & 1) * 16;
    const int csel = (wave >> 1) * 64;

    f32x4 acc[4];
#pragma unroll
    for (int i = 0; i < 4; ++i) acc[i] = (f32x4){0.f, 0.f, 0.f, 0.f};

    // ---- preload iter 0 ----
    f32x4 a = *(const f32x4*)(a_src);
    load_lds16(&sB[0][b_row0][0], b_src);
    load_lds16(&sB[0][b_row0 + 16][0], b_src + (size_t)16 * KTOT);

    const int NITER = KTOT / 32;
    for (int kt = 0; kt < NITER; ++kt) {
        const int cur = kt & 1;
        // ---- stage A: convert (+diag fix) -> LDS[cur] ----
        float av[4] = {a.x, a.y, a.z, a.w};
        if constexpr (!IS_XW) {
            int n  = n_local_base + a_row;
            int m0 = kt * 32 + a_col;
#pragma unroll
            for (int j = 0; j < 4; ++j)
                if (m0 + j == n) av[j] = 1.0f;   // A_hat diagonal = 1
        }
        bf16x4 apack;
#pragma unroll
        for (int j = 0; j < 4; ++j) apack[j] = (__bf16)av[j];
        *(bf16x4*)(&sA[cur][a_row][a_col]) = apack;

        __syncthreads();   // drains: my ds_write + my glds issued last iter

        // ---- issue NEXT iter's loads: in flight during MFMA phase ----
        if (kt + 1 < NITER) {
            const __bf16* bs = b_src + (size_t)(kt + 1) * 32;
            load_lds16(&sB[cur ^ 1][b_row0][0], bs);
            load_lds16(&sB[cur ^ 1][b_row0 + 16][0], bs + (size_t)16 * KTOT);
            a = *(const f32x4*)(a_src + (size_t)(kt + 1) * 32);
        }

        // ---- MFMA on buf[cur]: 16 rows x 64 cols per wave ----
        bf16x8 af = *(const bf16x8*)(&sA[cur][rsel + (lane & 15)][(lane >> 4) * 8]);
#pragma unroll
        for (int nb = 0; nb < 4; ++nb) {
            bf16x8 bfv = *(const bf16x8*)(
                &sB[cur][csel + nb * 16 + (lane & 15)][(lane >> 4) * 8]);
            acc[nb] = __builtin_amdgcn_mfma_f32_16x16x32_bf16(af, bfv, acc[nb], 0, 0, 0);
        }
        // no second barrier: kt+2's writes to buf[cur] happen after kt+1's
        // barrier, by which time every thread finished kt's reads of buf[cur]
    }

    // ---- epilogue: C/D layout col=lane&15, row=(lane>>4)*4+reg ----
    const int col0 = lane & 15;
    const int rq   = (lane >> 4) * 4;
#pragma unroll
    for (int r = 0; r < 4; ++r) {
        int grow = row_base + rsel + rq + r;     // flat row in [B*2048]
        float dr = dvec[grow];
        if constexpr (IS_XW) {
            int m_loc = grow - b * NN;
#pragma unroll
            for (int nb = 0; nb < 4; ++nb) {
                int o = csel + nb * 16 + col0;
                yt[((size_t)b * 128 + o) * NN + m_loc] = (__bf16)(acc[nb][r] * dr);
            }
        } else {
#pragma unroll
            for (int nb = 0; nb < 4; ++nb) {
                int o = csel + nb * 16 + col0;
                float v = acc[nb][r] * dr;
                out[(size_t)grow * 128 + o] = v > 0.f ? v : 0.f;
            }
        }
    }
}

extern "C" void kernel_launch(void* const* d_in, const int* in_sizes, int n_in,
                              void* d_out, int out_size, void* d_ws, size_t ws_size,
                              hipStream_t stream) {
    const float* x   = (const float*)d_in[0];   // [8,2048,128]
    const float* adj = (const float*)d_in[1];   // [8,2048,2048]
    const float* W   = (const float*)d_in[2];   // [128,128]
    float* out = (float*)d_out;

    char* ws = (char*)d_ws;
    float*  dvec = (float*)ws;                              // 64 KB
    __bf16* yt   = (__bf16*)(ws + 65536);                   // 8 MB  [B][128][2048]
    __bf16* Wt   = (__bf16*)(ws + 65536 + (size_t)NB * 128 * NN * 2);  // 32 KB

    hipLaunchKernelGGL(wt_kernel, dim3(64), dim3(256), 0, stream, W, Wt);
    hipLaunchKernelGGL(d_kernel, dim3(NB * NN / 4), dim3(256), 0, stream, adj, dvec);
    hipLaunchKernelGGL((gemm_kernel<128, true>), dim3(512), dim3(256), 0, stream,
                       x, Wt, dvec, (float*)nullptr, yt);
    hipLaunchKernelGGL((gemm_kernel<2048, false>), dim3(512), dim3(256), 0, stream,
                       adj, yt, dvec, out, (__bf16*)nullptr);
}